// Round 10
// baseline (371.256 us; speedup 1.0000x reference)
//
#include <hip/hip_runtime.h>
#include <hip/hip_bf16.h>
#include <hip/hip_fp16.h>

#define N_BUS   2000
#define BATCH   512
#define NNODES  (BATCH * N_BUS)      // 1,024,000
#define NEDGES  3072000
#define NXCD    8

constexpr float SN_INV     = 0.01f;                 // 1/SN_MVA
constexpr float ALPHA_C    = 0.9f;
constexpr float PHYS_SCALE = 0.02f;
constexpr float DEG2RAD_C  = 0.017453292519943295f;

typedef float v4f __attribute__((ext_vector_type(4)));   // nontemporal-load-compatible

// ---- EXPERIMENT: L2-local (SE-scope) packed f16 atomic ----
// No sc bits -> atomic performed in the local XCD's L2 (banked, high rate) instead of
// the memory-side unit (measured wall 19.7G tx/s chip-wide, R2/R3/R7/R9 invariant).
// Requires per-XCD privatized destination; kernel-end release flushes L2 for the next dispatch.
__device__ __forceinline__ void atomic_pk_add_h2_l2(__half2* addr, float P, float Q) {
    __half2 v = __floats2half2_rn(P, Q);
    unsigned u = *reinterpret_cast<unsigned*>(&v);
    asm volatile("global_atomic_pk_add_f16 %0, %1, off"
                 :: "v"(addr), "v"(u) : "memory");
}

__device__ __forceinline__ unsigned xcc_id() {
    unsigned x;
    asm("s_getreg_b32 %0, hwreg(HW_REG_XCC_ID)" : "=s"(x));
    return x & (NXCD - 1);
}

__device__ __forceinline__ float wave_reduce(float v) {
    #pragma unroll
    for (int off = 32; off > 0; off >>= 1) v += __shfl_down(v, off, 64);
    return v;
}

// ---------------- kernel 1: node prep (4 nodes/thread, all vector loads) ----------------
__global__ __launch_bounds__(256) void node_prep(
    const float* __restrict__ y_pred, const float* __restrict__ y_true,
    const float* __restrict__ y_mean, const float* __restrict__ y_std,
    __half2* __restrict__ ef, float* __restrict__ acc)
{
    int t = blockIdx.x * blockDim.x + threadIdx.x;
    int n0 = t * 4;
    int i0 = n0 % N_BUS;                       // multiple of 4 -> no wrap, aligned
    float4 pr0 = reinterpret_cast<const float4*>(y_pred + (size_t)n0*2)[0];
    float4 pr1 = reinterpret_cast<const float4*>(y_pred + (size_t)n0*2)[1];
    float4 tr0 = reinterpret_cast<const float4*>(y_true + (size_t)n0*2)[0];
    float4 tr1 = reinterpret_cast<const float4*>(y_true + (size_t)n0*2)[1];
    float4 ys0 = reinterpret_cast<const float4*>(y_std  + (size_t)i0*2)[0];
    float4 ys1 = reinterpret_cast<const float4*>(y_std  + (size_t)i0*2)[1];
    float4 ym0 = reinterpret_cast<const float4*>(y_mean + (size_t)i0*2)[0];
    float4 ym1 = reinterpret_cast<const float4*>(y_mean + (size_t)i0*2)[1];

    float d, msep = 0.0f;
    d = (pr0.x - tr0.x) * ys0.x; msep = fmaf(d, d, msep);
    d = (pr0.y - tr0.y) * ys0.y; msep = fmaf(d, d, msep);
    d = (pr0.z - tr0.z) * ys0.z; msep = fmaf(d, d, msep);
    d = (pr0.w - tr0.w) * ys0.w; msep = fmaf(d, d, msep);
    d = (pr1.x - tr1.x) * ys1.x; msep = fmaf(d, d, msep);
    d = (pr1.y - tr1.y) * ys1.y; msep = fmaf(d, d, msep);
    d = (pr1.z - tr1.z) * ys1.z; msep = fmaf(d, d, msep);
    d = (pr1.w - tr1.w) * ys1.w; msep = fmaf(d, d, msep);

    float vmA = fmaf(pr0.x, ys0.x, ym0.x), vaA = fmaf(pr0.y, ys0.y, ym0.y);
    float vmB = fmaf(pr0.z, ys0.z, ym0.z), vaB = fmaf(pr0.w, ys0.w, ym0.w);
    float vmC = fmaf(pr1.x, ys1.x, ym1.x), vaC = fmaf(pr1.y, ys1.y, ym1.y);
    float vmD = fmaf(pr1.z, ys1.z, ym1.z), vaD = fmaf(pr1.w, ys1.w, ym1.w);
    float s, c;
    __sincosf(vaA * DEG2RAD_C, &s, &c); __half2 eA = __floats2half2_rn(vmA*c, vmA*s);
    __sincosf(vaB * DEG2RAD_C, &s, &c); __half2 eB = __floats2half2_rn(vmB*c, vmB*s);
    __sincosf(vaC * DEG2RAD_C, &s, &c); __half2 eC = __floats2half2_rn(vmC*c, vmC*s);
    __sincosf(vaD * DEG2RAD_C, &s, &c); __half2 eD = __floats2half2_rn(vmD*c, vmD*s);
    *reinterpret_cast<uint4*>(ef + n0) = make_uint4(
        *reinterpret_cast<unsigned*>(&eA), *reinterpret_cast<unsigned*>(&eB),
        *reinterpret_cast<unsigned*>(&eC), *reinterpret_cast<unsigned*>(&eD));

    __shared__ float red[4];
    float v = wave_reduce(msep);
    int lane = threadIdx.x & 63, wid = threadIdx.x >> 6;
    if (lane == 0) red[wid] = v;
    __syncthreads();
    if (threadIdx.x == 0)
        unsafeAtomicAdd(acc + 0, red[0] + red[1] + red[2] + red[3]);
}

// ---------------- kernel 2: per-edge message + L2-local scatter into per-XCD copy ----------------
__global__ __launch_bounds__(256) void edge_kernel(
    const int* __restrict__ eidx, const float* __restrict__ eattr,
    const float* __restrict__ e_mean, const float* __restrict__ e_std,
    const __half2* __restrict__ ef, __half2* __restrict__ agg8)
{
    __half2* myagg = agg8 + (size_t)xcc_id() * NNODES;   // this XCD's private copy
    int e = blockIdx.x * blockDim.x + threadIdx.x;
    int s = __builtin_nontemporal_load(eidx + e);
    int d = __builtin_nontemporal_load(eidx + NEDGES + e);
    const v4f* eav = reinterpret_cast<const v4f*>(eattr) + e;
    v4f ea = __builtin_nontemporal_load(eav);
    float Gs = fmaf(ea.x, e_std[0], e_mean[0]);
    float Bs = fmaf(ea.y, e_std[1], e_mean[1]);
    float Gm = fmaf(ea.z, e_std[2], e_mean[2]);
    float Bm = fmaf(ea.w, e_std[3], e_mean[3]);
    float2 fi = __half22float2(ef[s]);   // (e_i, f_i)
    float2 fj = __half22float2(ef[d]);   // (e_j, f_j)
    float e_i = fi.x, f_i = fi.y;
    float e_j = fj.x, f_j = fj.y;
    float I_re = Gs*e_i - Bs*f_i + Gm*e_j - Bm*f_j;
    float I_im = Gs*f_i + Bs*e_i + Gm*f_j + Bm*e_j;
    float Pji = -(e_i*I_re + f_i*I_im);
    float Qji = -(f_i*I_re - e_i*I_im);
    atomic_pk_add_h2_l2(myagg + s, Pji, Qji);
}

// per-node imbalance term; vm^2 recomputed from half ef (rel err ~1e-3 on a ~0.01-weight term)
__device__ __forceinline__ void node_term(
    unsigned efb, float agx, float agy, float shP, float shQ, int m, long n, int i,
    const float* __restrict__ x_input, const float* __restrict__ x_mean,
    const float* __restrict__ x_std, float& sqw, float& wsum)
{
    float2 efk = __half22float2(*reinterpret_cast<__half2*>(&efb));
    float vm2 = fmaf(efk.x, efk.x, efk.y * efk.y);
    float p = fmaf(x_input[n*7 + 0], x_std[i*7 + 0], x_mean[i*7 + 0]) * SN_INV;
    float q = fmaf(x_input[n*7 + 1], x_std[i*7 + 1], x_mean[i*7 + 1]) * SN_INV;
    float dP = fmaf(vm2, shP, p) - agx;
    float dQ = fmaf(-vm2, shQ, q) - agy;
    float w = m ? 1.0f : 0.0f;
    sqw = fmaf(dP*dP + dQ*dQ, w, sqw);
    wsum += w;
}

// ---------------- kernel 3: node finalize (4 nodes/thread, sums 8 agg copies) + combine ----------------
__global__ __launch_bounds__(256) void node_final(
    const float* __restrict__ x_input,
    const float* __restrict__ x_mean, const float* __restrict__ x_std,
    const float* __restrict__ shunt, const int* __restrict__ mask,
    const __half2* __restrict__ ef, const __half2* __restrict__ agg8,
    float* __restrict__ acc, float* __restrict__ out)
{
    int t = blockIdx.x * blockDim.x + threadIdx.x;
    int n0 = t * 4;
    int i0 = n0 % N_BUS;
    uint4 efu = *reinterpret_cast<const uint4*>(ef + n0);

    // sum the 8 per-XCD partial aggregates (f32 accumulation)
    float agx[4] = {0,0,0,0}, agy[4] = {0,0,0,0};
    #pragma unroll
    for (int k = 0; k < NXCD; ++k) {
        uint4 a = *reinterpret_cast<const uint4*>(agg8 + (size_t)k * NNODES + n0);
        float2 a0 = __half22float2(*reinterpret_cast<__half2*>(&a.x));
        float2 a1 = __half22float2(*reinterpret_cast<__half2*>(&a.y));
        float2 a2 = __half22float2(*reinterpret_cast<__half2*>(&a.z));
        float2 a3 = __half22float2(*reinterpret_cast<__half2*>(&a.w));
        agx[0] += a0.x; agy[0] += a0.y;
        agx[1] += a1.x; agy[1] += a1.y;
        agx[2] += a2.x; agy[2] += a2.y;
        agx[3] += a3.x; agy[3] += a3.y;
    }

    float4 sh0 = reinterpret_cast<const float4*>(shunt + (size_t)i0*2)[0];
    float4 sh1 = reinterpret_cast<const float4*>(shunt + (size_t)i0*2)[1];
    int4  mk  = *reinterpret_cast<const int4*>(mask + i0);

    float sqw = 0.0f, wsum = 0.0f;
    node_term(efu.x, agx[0], agy[0], sh0.x, sh0.y, mk.x, (long)n0+0, i0+0, x_input, x_mean, x_std, sqw, wsum);
    node_term(efu.y, agx[1], agy[1], sh0.z, sh0.w, mk.y, (long)n0+1, i0+1, x_input, x_mean, x_std, sqw, wsum);
    node_term(efu.z, agx[2], agy[2], sh1.x, sh1.y, mk.z, (long)n0+2, i0+2, x_input, x_mean, x_std, sqw, wsum);
    node_term(efu.w, agx[3], agy[3], sh1.z, sh1.w, mk.w, (long)n0+3, i0+3, x_input, x_mean, x_std, sqw, wsum);

    __shared__ float red0[4], red1[4];
    float v0 = wave_reduce(sqw);
    float v1 = wave_reduce(wsum);
    int lane = threadIdx.x & 63, wid = threadIdx.x >> 6;
    if (lane == 0) { red0[wid] = v0; red1[wid] = v1; }
    __syncthreads();
    if (threadIdx.x == 0) {
        unsafeAtomicAdd(acc + 1, red0[0] + red0[1] + red0[2] + red0[3]);
        unsafeAtomicAdd(acc + 2, red1[0] + red1[1] + red1[2] + red1[3]);
        __threadfence();
        unsigned prev = atomicAdd(reinterpret_cast<unsigned*>(acc + 3), 1u);
        if (prev == gridDim.x - 1) {
            float mse = unsafeAtomicAdd(acc + 0, 0.0f) * (1.0f / (2.0f * NNODES));
            float sq  = unsafeAtomicAdd(acc + 1, 0.0f);
            float ww  = unsafeAtomicAdd(acc + 2, 0.0f);
            out[0] = ALPHA_C * mse + (1.0f - ALPHA_C) * PHYS_SCALE * (sq / ww);
        }
    }
}

extern "C" void kernel_launch(void* const* d_in, const int* in_sizes, int n_in,
                              void* d_out, int out_size, void* d_ws, size_t ws_size,
                              hipStream_t stream) {
    const float* y_pred    = (const float*)d_in[0];
    const float* y_true    = (const float*)d_in[1];
    const float* x_input   = (const float*)d_in[2];
    const int*   edge_idx  = (const int*)  d_in[3];
    const float* edge_attr = (const float*)d_in[4];
    const float* x_mean    = (const float*)d_in[5];
    const float* x_std     = (const float*)d_in[6];
    const float* y_mean    = (const float*)d_in[7];
    const float* y_std     = (const float*)d_in[8];
    const float* edge_mean = (const float*)d_in[9];
    const float* edge_std  = (const float*)d_in[10];
    const int*   load_mask = (const int*)  d_in[11];
    const float* shunt     = (const float*)d_in[12];

    // ws layout: agg8 half2[8][N] (32 MB) | ef half2[N] (4 MB) | acc float[4]
    __half2* agg8 = (__half2*)d_ws;
    __half2* ef   = agg8 + (size_t)NXCD * NNODES;
    float*   acc  = (float*)(ef + NNODES);

    (void)hipMemsetAsync(agg8, 0, (size_t)NXCD * NNODES * sizeof(__half2), stream);
    (void)hipMemsetAsync(acc, 0, 16, stream);

    dim3 blk(256);
    node_prep<<<dim3(NNODES / 1024), blk, 0, stream>>>(
        y_pred, y_true, y_mean, y_std, ef, acc);
    edge_kernel<<<dim3(NEDGES / 256), blk, 0, stream>>>(
        edge_idx, edge_attr, edge_mean, edge_std, ef, agg8);
    node_final<<<dim3(NNODES / 1024), blk, 0, stream>>>(
        x_input, x_mean, x_std, shunt, load_mask, ef, agg8, acc, (float*)d_out);
}